// Round 1
// baseline (518.616 us; speedup 1.0000x reference)
//
#include <hip/hip_runtime.h>
#include <hip/hip_bf16.h>

// FP8LinearBase: y[M,N] = x[M,K] @ (w[N,K] * s[n/128,k/128])^T
// M=8192, K=4096, N=4096, fp32 in/out.
// Plan: pass1 convert x->bf16, pass2 dequant+convert w->bf16 (both into d_ws),
// pass3 bf16 MFMA GEMM (128x128 tile, BK=64, global_load_lds + XOR swizzle).

#define MD 8192
#define ND 4096
#define KD 4096

typedef unsigned short u16;
typedef short bf16x8 __attribute__((ext_vector_type(8)));   // 8 bf16 = 4 VGPR
typedef float f32x4 __attribute__((ext_vector_type(4)));

__device__ __forceinline__ u16 f2bf(float f) {
  // round-to-nearest-even fp32 -> bf16 (inputs are finite normals; no NaN path)
  union { float f; unsigned int u; } a; a.f = f;
  unsigned int u = a.u;
  u += 0x7fffu + ((u >> 16) & 1u);
  return (u16)(u >> 16);
}

// ---- pass 1: x fp32 -> bf16 --------------------------------------------------
__global__ void k_cvt_x(const float4* __restrict__ x, ushort4* __restrict__ o, int n4) {
  int i = blockIdx.x * blockDim.x + threadIdx.x;
  int st = gridDim.x * blockDim.x;
  for (; i < n4; i += st) {
    float4 v = x[i];
    ushort4 r;
    r.x = f2bf(v.x); r.y = f2bf(v.y); r.z = f2bf(v.z); r.w = f2bf(v.w);
    o[i] = r;
  }
}

// ---- pass 2: w fp32 * block-scale -> bf16 -----------------------------------
__global__ void k_cvt_w(const float4* __restrict__ w, const float* __restrict__ s,
                        ushort4* __restrict__ o, int n4) {
  int i = blockIdx.x * blockDim.x + threadIdx.x;
  int st = gridDim.x * blockDim.x;
  for (; i < n4; i += st) {
    int n  = i >> 10;        // / (K/4 = 1024)
    int k4 = i & 1023;
    float sc = s[(n >> 7) * (KD / 128) + (k4 >> 5)];  // k = 4*k4; k>>7 == k4>>5
    float4 v = w[i];
    ushort4 r;
    r.x = f2bf(v.x * sc); r.y = f2bf(v.y * sc); r.z = f2bf(v.z * sc); r.w = f2bf(v.w * sc);
    o[i] = r;
  }
}

// ---- pass 3: bf16 GEMM, C[M,N] = A[M,K] * B[N,K]^T --------------------------
// 128x128 tile, BK=64. 4 waves in 2x2, each wave owns a 64x64 sub-tile
// (4x4 fragments of 16x16, mfma_f32_16x16x32_bf16).
// LDS tiles [128 rows][64 bf16] = 128B/row; 16B chunks XOR-swizzled kb^= (row&7)
// (G4 fix; linear LDS dest for global_load_lds, inverse-swizzled GLOBAL source).
__global__ __launch_bounds__(256) void k_gemm(const u16* __restrict__ A,
                                              const u16* __restrict__ B,
                                              float* __restrict__ C) {
  __shared__ u16 As[128 * 64];
  __shared__ u16 Bs[128 * 64];

  const int tid  = threadIdx.x;
  const int lane = tid & 63;
  const int wid  = tid >> 6;
  const int wr   = wid >> 1;          // wave row 0..1
  const int wc   = wid & 1;           // wave col 0..1
  const int bm   = blockIdx.x >> 5;   // N/128 = 32 tiles -> 5 bits
  const int bn   = blockIdx.x & 31;
  const long brow = (long)bm * 128;
  const long bcol = (long)bn * 128;

  f32x4 acc[4][4] = {};

  for (int kt = 0; kt < KD / 64; ++kt) {
    if (kt) __syncthreads();          // all waves done reading LDS from prev iter
    // stage: A tile 128x64 bf16 (16KB) + B tile (16KB); 4 issues each,
    // 256 thr x 16B per issue. chunk c -> (row = c>>3, kb = c&7).
#pragma unroll
    for (int i = 0; i < 4; ++i) {
      int c   = i * 256 + tid;
      int row = c >> 3;
      int kb  = c & 7;
      int kbs = kb ^ (row & 7);       // inverse swizzle on the global source
      const u16* srcA = A + (brow + row) * KD + kt * 64 + kbs * 8;
      const u16* srcB = B + (bcol + row) * KD + kt * 64 + kbs * 8;
      __builtin_amdgcn_global_load_lds(
          (const __attribute__((address_space(1))) unsigned int*)srcA,
          (__attribute__((address_space(3))) unsigned int*)&As[c * 8], 16, 0, 0);
      __builtin_amdgcn_global_load_lds(
          (const __attribute__((address_space(1))) unsigned int*)srcB,
          (__attribute__((address_space(3))) unsigned int*)&Bs[c * 8], 16, 0, 0);
    }
    __syncthreads();                  // compiler drains vmcnt(0) before s_barrier

#pragma unroll
    for (int ks = 0; ks < 2; ++ks) {
      bf16x8 af[4], bfv[4];
      const int kq = ks * 4 + (lane >> 4);     // 16B k-chunk this lane reads
#pragma unroll
      for (int mi = 0; mi < 4; ++mi) {
        int r = wr * 64 + mi * 16 + (lane & 15);
        af[mi] = *(const bf16x8*)&As[r * 64 + (kq ^ (r & 7)) * 8];
      }
#pragma unroll
      for (int ni = 0; ni < 4; ++ni) {
        int r = wc * 64 + ni * 16 + (lane & 15);
        bfv[ni] = *(const bf16x8*)&Bs[r * 64 + (kq ^ (r & 7)) * 8];
      }
#pragma unroll
      for (int mi = 0; mi < 4; ++mi)
#pragma unroll
        for (int ni = 0; ni < 4; ++ni)
          acc[mi][ni] = __builtin_amdgcn_mfma_f32_16x16x32_bf16(
              af[mi], bfv[ni], acc[mi][ni], 0, 0, 0);
    }
  }

  // C/D layout (m89-verified): col = lane&15, row = (lane>>4)*4 + reg
  const int r0 = (lane >> 4) * 4;
  const int c0 = lane & 15;
#pragma unroll
  for (int mi = 0; mi < 4; ++mi)
#pragma unroll
    for (int ni = 0; ni < 4; ++ni) {
      long row = brow + wr * 64 + mi * 16 + r0;
      long col = bcol + wc * 64 + ni * 16 + c0;
      float* p = C + row * ND + col;
#pragma unroll
      for (int j = 0; j < 4; ++j) p[(long)j * ND] = acc[mi][ni][j];
    }
}

// ---- insurance: correct fp32 path if workspace is too small -----------------
__global__ void k_fallback(const float* __restrict__ x, const float* __restrict__ w,
                           const float* __restrict__ s, float* __restrict__ out) {
  __shared__ float Ax[16][16];
  __shared__ float Bw[16][17];
  int tx = threadIdx.x, ty = threadIdx.y;
  long row = blockIdx.y * 16 + ty;
  long col = blockIdx.x * 16 + tx;
  float acc = 0.f;
  for (int kt = 0; kt < KD; kt += 16) {
    Ax[ty][tx] = x[row * KD + kt + tx];
    long wn = blockIdx.x * 16 + ty;
    Bw[ty][tx] = w[wn * KD + kt + tx] * s[(wn >> 7) * (KD / 128) + ((kt + tx) >> 7)];
    __syncthreads();
#pragma unroll
    for (int kk = 0; kk < 16; ++kk) acc += Ax[ty][kk] * Bw[tx][kk];
    __syncthreads();
  }
  out[row * ND + col] = acc;
}

extern "C" void kernel_launch(void* const* d_in, const int* in_sizes, int n_in,
                              void* d_out, int out_size, void* d_ws, size_t ws_size,
                              hipStream_t stream) {
  const float* x = (const float*)d_in[0];
  const float* w = (const float*)d_in[1];
  const float* s = (const float*)d_in[2];
  float* out = (float*)d_out;

  const size_t xb_bytes = (size_t)MD * KD * 2;   // 67,108,864
  const size_t wb_bytes = (size_t)ND * KD * 2;   // 33,554,432

  if (ws_size >= xb_bytes + wb_bytes) {
    u16* xb = (u16*)d_ws;
    u16* wb = (u16*)((char*)d_ws + xb_bytes);
    k_cvt_x<<<2048, 256, 0, stream>>>((const float4*)x, (ushort4*)xb, MD * KD / 4);
    k_cvt_w<<<2048, 256, 0, stream>>>((const float4*)w, s, (ushort4*)wb, ND * KD / 4);
    k_gemm<<<(MD / 128) * (ND / 128), 256, 0, stream>>>(xb, wb, out);
  } else {
    dim3 g(ND / 16, MD / 16), b(16, 16);
    k_fallback<<<g, b, 0, stream>>>(x, w, s, out);
  }
}

// Round 2
// 495.838 us; speedup vs baseline: 1.0459x; 1.0459x over previous
//
#include <hip/hip_runtime.h>
#include <hip/hip_bf16.h>

// FP8LinearBase: y[M,N] = x[M,K] @ (w[N,K] * s[n/128,k/128])^T
// M=8192, K=4096, N=4096, fp32 in/out.
// pass1: fused convert x->bf16 and dequant w->bf16 into d_ws (one kernel).
// pass2: bf16 GEMM, 256x256 tile, BK=64, 8-phase schedule (T2/T3/T4/T5):
//   8 waves (2Mx4N), 128KB LDS double-buffered in half-tiles, counted vmcnt,
//   raw s_barrier + lgkmcnt(0) + setprio(1) around 16-MFMA clusters.

#define MD 8192
#define ND 4096
#define KD 4096

typedef unsigned short u16;
typedef u16 u16x8 __attribute__((ext_vector_type(8)));
typedef short bf16x8 __attribute__((ext_vector_type(8)));   // 8 bf16 = 4 VGPR
typedef float f32x4 __attribute__((ext_vector_type(4)));

__device__ __forceinline__ u16 f2bf(float f) {
  union { float f; unsigned int u; } a; a.f = f;
  unsigned int u = a.u;
  u += 0x7fffu + ((u >> 16) & 1u);
  return (u16)(u >> 16);
}

__device__ __forceinline__ u16x8 pack8(float4 a, float4 b, float sc) {
  u16x8 r;
  r[0] = f2bf(a.x * sc); r[1] = f2bf(a.y * sc); r[2] = f2bf(a.z * sc); r[3] = f2bf(a.w * sc);
  r[4] = f2bf(b.x * sc); r[5] = f2bf(b.y * sc); r[6] = f2bf(b.z * sc); r[7] = f2bf(b.w * sc);
  return r;
}

// ---- pass 1: fused x->bf16 and w*scale->bf16 --------------------------------
// chunk = 8 elements. XC x-chunks then WC w-chunks; both divisible by grid
// stride (524288) so no intra-wave path divergence.
__global__ __launch_bounds__(256) void k_cvt(const float4* __restrict__ x,
                                             const float4* __restrict__ w,
                                             const float* __restrict__ s,
                                             u16x8* __restrict__ xb,
                                             u16x8* __restrict__ wb) {
  const int XC = MD * (KD / 8);   // 4,194,304
  const int WC = ND * (KD / 8);   // 2,097,152
  int i = blockIdx.x * blockDim.x + threadIdx.x;
  int st = gridDim.x * blockDim.x;
  for (; i < XC + WC; i += st) {
    if (i < XC) {
      xb[i] = pack8(x[2 * i], x[2 * i + 1], 1.0f);
    } else {
      int c = i - XC;
      int k8 = c & 511;           // K/8 = 512 chunks per w-row
      int n  = c >> 9;
      float sc = s[(n >> 7) * (KD / 128) + (k8 >> 4)];
      wb[c] = pack8(w[2 * c], w[2 * c + 1], sc);
    }
  }
}

// ---- pass 2: bf16 GEMM, 256x256 tile, 8-phase -------------------------------
// LDS: lds[buf][region][128*64] bf16; regions 0=A0,1=A1,2=B0,3=B1 (half-tiles,
// 128 rows x 64 bf16 = 128B/row, 16B chunks stored at kb^(row&7) -> 0 bank
// conflicts, verified round 1). Staging stream (derived, race-checked on
// paper): tile t phases stage P1:(t+1).A0, P2:(t+1).A1 -> other buffer;
// P3:(t+2).B0, P4:(t+2).B1 -> current buffer (B regions read-dead after P2).
// One vmcnt(4) per K-tile at P4 (2 half-tiles = 4 loads may stay in flight);
// vmcnt(0) only at t==NT-2.
__device__ __forceinline__ void stage_half(const u16* __restrict__ gbase,
                                           u16* lds_region, int tid) {
#pragma unroll
  for (int i = 0; i < 2; ++i) {
    int c   = i * 512 + tid;
    int row = c >> 3;
    int kb  = c & 7;
    int kbs = kb ^ (row & 7);     // inverse swizzle on the global source
    const u16* src = gbase + (long)row * KD + kbs * 8;
    __builtin_amdgcn_global_load_lds(
        (const __attribute__((address_space(1))) unsigned int*)src,
        (__attribute__((address_space(3))) unsigned int*)&lds_region[c * 8], 16, 0, 0);
  }
}

__device__ __forceinline__ bf16x8 ldfrag(const u16* reg, int rr, int kq) {
  return *(const bf16x8*)&reg[rr * 64 + ((kq ^ (rr & 7)) << 3)];
}

__global__ __launch_bounds__(512, 2) void k_gemm(const u16* __restrict__ A,
                                                 const u16* __restrict__ B,
                                                 float* __restrict__ C) {
  __shared__ u16 lds[2][4][128 * 64];   // 128 KiB -> 1 block/CU

  const int tid  = threadIdx.x;
  const int lane = tid & 63;
  const int wid  = tid >> 6;            // 0..7
  const int wr   = wid >> 2;            // 0..1  (M half)
  const int wc   = wid & 3;             // 0..3  (N quarter)
  const int l15  = lane & 15;
  const int l4h  = lane >> 4;           // 0..3

  // XCD-aware chunked swizzle (512 blocks, 64 per XCD), column-major tiles
  // so each XCD works one 2MB B-panel at a time (L2-resident).
  const int nbid = (blockIdx.x & 7) * 64 + (blockIdx.x >> 3);
  const int bm   = nbid & 31;           // M tile 0..31
  const int bnt  = nbid >> 5;           // N tile 0..15
  const long brow = (long)bm * 256;
  const long bcol = (long)bnt * 256;

  const int regA = wr;                  // 0 -> A0, 1 -> A1
  const int regB = 2 + (wc >> 1);       // 2 -> B0, 3 -> B1
  const int rB0  = (wc & 1) * 64;       // row base within B region

  f32x4 acc[8][4] = {};
  bf16x8 af[4], bf0[4], bf1[4];

  const int NT = KD / 64;               // 64 K-tiles

  // ---- prologue: stream order 0.B0, 0.B1, 0.A0, 0.A1, 1.B0, 1.B1 ----
  stage_half(B + bcol * KD, lds[0][2], tid);
  stage_half(B + (bcol + 128) * KD, lds[0][3], tid);
  stage_half(A + brow * KD, lds[0][0], tid);
  stage_half(A + (brow + 128) * KD, lds[0][1], tid);
  stage_half(B + bcol * KD + 64, lds[1][2], tid);
  stage_half(B + (bcol + 128) * KD + 64, lds[1][3], tid);
  asm volatile("s_waitcnt vmcnt(4)" ::: "memory");   // tile 0 fully arrived
  __builtin_amdgcn_s_barrier();

  for (int t = 0; t < NT; ++t) {
    const int b  = t & 1;
    const int bo = b ^ 1;
    const u16* Ar = &lds[b][regA][0];
    const u16* Br = &lds[b][regB][0];
    const long knext1 = (long)(t + 1) * 64;
    const long knext2 = (long)(t + 2) * 64;

    // ---------- P1: ks0, mi 0-3 ----------
#pragma unroll
    for (int i = 0; i < 4; ++i) af[i]  = ldfrag(Ar, i * 16 + l15, l4h);
#pragma unroll
    for (int i = 0; i < 4; ++i) bf0[i] = ldfrag(Br, rB0 + i * 16 + l15, l4h);
    if (t + 1 < NT) stage_half(A + brow * KD + knext1, lds[bo][0], tid);
    __builtin_amdgcn_s_barrier();
    asm volatile("s_waitcnt lgkmcnt(0)" ::: "memory");
    __builtin_amdgcn_s_setprio(1);
#pragma unroll
    for (int mi = 0; mi < 4; ++mi)
#pragma unroll
      for (int ni = 0; ni < 4; ++ni)
        acc[mi][ni] = __builtin_amdgcn_mfma_f32_16x16x32_bf16(af[mi], bf0[ni], acc[mi][ni], 0, 0, 0);
    __builtin_amdgcn_s_setprio(0);
    __builtin_amdgcn_s_barrier();

    // ---------- P2: ks1, mi 0-3 ----------
#pragma unroll
    for (int i = 0; i < 4; ++i) af[i]  = ldfrag(Ar, i * 16 + l15, 4 + l4h);
#pragma unroll
    for (int i = 0; i < 4; ++i) bf1[i] = ldfrag(Br, rB0 + i * 16 + l15, 4 + l4h);
    if (t + 1 < NT) stage_half(A + (brow + 128) * KD + knext1, lds[bo][1], tid);
    __builtin_amdgcn_s_barrier();
    asm volatile("s_waitcnt lgkmcnt(0)" ::: "memory");
    __builtin_amdgcn_s_setprio(1);
#pragma unroll
    for (int mi = 0; mi < 4; ++mi)
#pragma unroll
      for (int ni = 0; ni < 4; ++ni)
        acc[mi][ni] = __builtin_amdgcn_mfma_f32_16x16x32_bf16(af[mi], bf1[ni], acc[mi][ni], 0, 0, 0);
    __builtin_amdgcn_s_setprio(0);
    __builtin_amdgcn_s_barrier();

    // ---------- P3: ks0, mi 4-7 (reuses bf0) ----------
#pragma unroll
    for (int i = 0; i < 4; ++i) af[i] = ldfrag(Ar, 64 + i * 16 + l15, l4h);
    if (t + 2 < NT) stage_half(B + bcol * KD + knext2, lds[b][2], tid);
    __builtin_amdgcn_s_barrier();
    asm volatile("s_waitcnt lgkmcnt(0)" ::: "memory");
    __builtin_amdgcn_s_setprio(1);
#pragma unroll
    for (int mi = 0; mi < 4; ++mi)
#pragma unroll
      for (int ni = 0; ni < 4; ++ni)
        acc[4 + mi][ni] = __builtin_amdgcn_mfma_f32_16x16x32_bf16(af[mi], bf0[ni], acc[4 + mi][ni], 0, 0, 0);
    __builtin_amdgcn_s_setprio(0);
    __builtin_amdgcn_s_barrier();

    // ---------- P4: ks1, mi 4-7 (reuses bf1) ----------
#pragma unroll
    for (int i = 0; i < 4; ++i) af[i] = ldfrag(Ar, 64 + i * 16 + l15, 4 + l4h);
    if (t + 2 < NT) stage_half(B + (bcol + 128) * KD + knext2, lds[b][3], tid);
    __builtin_amdgcn_s_barrier();
    asm volatile("s_waitcnt lgkmcnt(0)" ::: "memory");
    __builtin_amdgcn_s_setprio(1);
#pragma unroll
    for (int mi = 0; mi < 4; ++mi)
#pragma unroll
      for (int ni = 0; ni < 4; ++ni)
        acc[4 + mi][ni] = __builtin_amdgcn_mfma_f32_16x16x32_bf16(af[mi], bf1[ni], acc[4 + mi][ni], 0, 0, 0);
    __builtin_amdgcn_s_setprio(0);
    // counted vmcnt: everything staged through this tile's P2 must be in LDS
    // before next tile's reads; P3/P4 stages (4 loads) may stay in flight.
    if (t < NT - 2) {
      asm volatile("s_waitcnt vmcnt(4)" ::: "memory");
    } else {
      asm volatile("s_waitcnt vmcnt(0)" ::: "memory");
    }
    __builtin_amdgcn_s_barrier();
  }

  // ---- epilogue: C/D layout col=lane&15, row=(lane>>4)*4+j (m89-verified) ----
  const int r0 = l4h * 4;
#pragma unroll
  for (int mi = 0; mi < 8; ++mi)
#pragma unroll
    for (int ni = 0; ni < 4; ++ni) {
      long row = brow + wr * 128 + mi * 16 + r0;
      long col = bcol + wc * 64 + ni * 16 + l15;
      float* p = C + row * ND + col;
#pragma unroll
      for (int j = 0; j < 4; ++j) p[(long)j * ND] = acc[mi][ni][j];
    }
}

// ---- insurance: correct fp32 path if workspace is too small -----------------
__global__ void k_fallback(const float* __restrict__ x, const float* __restrict__ w,
                           const float* __restrict__ s, float* __restrict__ out) {
  __shared__ float Ax[16][16];
  __shared__ float Bw[16][17];
  int tx = threadIdx.x, ty = threadIdx.y;
  long row = blockIdx.y * 16 + ty;
  long col = blockIdx.x * 16 + tx;
  float acc = 0.f;
  for (int kt = 0; kt < KD; kt += 16) {
    Ax[ty][tx] = x[row * KD + kt + tx];
    long wn = blockIdx.x * 16 + ty;
    Bw[ty][tx] = w[wn * KD + kt + tx] * s[(wn >> 7) * (KD / 128) + ((kt + tx) >> 7)];
    __syncthreads();
#pragma unroll
    for (int kk = 0; kk < 16; ++kk) acc += Ax[ty][kk] * Bw[tx][kk];
    __syncthreads();
  }
  out[row * ND + col] = acc;
}

extern "C" void kernel_launch(void* const* d_in, const int* in_sizes, int n_in,
                              void* d_out, int out_size, void* d_ws, size_t ws_size,
                              hipStream_t stream) {
  const float* x = (const float*)d_in[0];
  const float* w = (const float*)d_in[1];
  const float* s = (const float*)d_in[2];
  float* out = (float*)d_out;

  const size_t xb_bytes = (size_t)MD * KD * 2;
  const size_t wb_bytes = (size_t)ND * KD * 2;

  if (ws_size >= xb_bytes + wb_bytes) {
    u16* xb = (u16*)d_ws;
    u16* wb = (u16*)((char*)d_ws + xb_bytes);
    k_cvt<<<2048, 256, 0, stream>>>((const float4*)x, (const float4*)w, s,
                                    (u16x8*)xb, (u16x8*)wb);
    k_gemm<<<(MD / 256) * (ND / 256), 512, 0, stream>>>(xb, wb, out);
  } else {
    dim3 g(ND / 16, MD / 16), b(16, 16);
    k_fallback<<<g, b, 0, stream>>>(x, w, s, out);
  }
}